// Round 2
// baseline (43269.363 us; speedup 1.0000x reference)
//
#include <hip/hip_runtime.h>
#include <math.h>

#define TQ 256
#define DQ 512
#define GQ 2048
#define NWG 256

// ---------------- embedding + predicate concat -> xT[t][d][b] ----------------
__global__ __launch_bounds__(256) void k_embed(const int* __restrict__ wid,
                                               const int* __restrict__ pid,
                                               const float* __restrict__ emb,
                                               float* __restrict__ xT) {
    __shared__ float Ls[64][65];
    int t = blockIdx.x;
    int d0 = blockIdx.y * 64;
    int tid = threadIdx.x;
    int l = tid & 63;
    int grp = tid >> 6;
#pragma unroll 4
    for (int bb = 0; bb < 16; ++bb) {
        int b = grp * 16 + bb;
        int d = d0 + l;
        float v;
        if (d < 511) v = emb[(size_t)wid[b * TQ + t] * 511 + d];
        else         v = (float)pid[b * TQ + t];
        Ls[l][b] = v;
    }
    __syncthreads();
#pragma unroll 4
    for (int dd = 0; dd < 16; ++dd) {
        int dl = grp * 16 + dd;
        xT[((size_t)t * DQ + d0 + dl) * 64 + l] = Ls[dl][l];
    }
}

// ---------------- preT[sl][col][b] = xT(t_in) @ W + b ----------------
__global__ __launch_bounds__(256) void k_pre(const float* __restrict__ xT,
                                             const float* __restrict__ W,
                                             const float* __restrict__ bias,
                                             float* __restrict__ preT,
                                             int s0, int flip) {
    __shared__ float As[16][68];   // [k][b]
    __shared__ float Bs[16][68];   // [k][n]
    int sl = blockIdx.x;
    int nt = blockIdx.y;
    int s = s0 + sl;
    int t_in = flip ? (TQ - 1 - s) : s;
    int tid = threadIdx.x;
    int tr = tid >> 4;              // 0..15 -> b quad
    int tc = tid & 15;              // 0..15 -> n quad
    int lk = tid >> 4;              // 0..15 (k row for loads)
    int lb4 = (tid & 15) * 4;

    float acc[4][4];
#pragma unroll
    for (int i = 0; i < 4; ++i)
#pragma unroll
        for (int j = 0; j < 4; ++j) acc[i][j] = 0.f;

    const float* xTt = xT + (size_t)t_in * DQ * 64;

    for (int kt = 0; kt < DQ; kt += 16) {
        *(float4*)&As[lk][lb4] = *(const float4*)&xTt[(size_t)(kt + lk) * 64 + lb4];
        *(float4*)&Bs[lk][lb4] = *(const float4*)&W[(size_t)(kt + lk) * GQ + nt * 64 + lb4];
        __syncthreads();
#pragma unroll
        for (int k = 0; k < 16; ++k) {
            float4 av = *(const float4*)&As[k][tr * 4];
            float4 bv = *(const float4*)&Bs[k][tc * 4];
            float a[4] = {av.x, av.y, av.z, av.w};
            float b[4] = {bv.x, bv.y, bv.z, bv.w};
#pragma unroll
            for (int i = 0; i < 4; ++i)
#pragma unroll
                for (int j = 0; j < 4; ++j) acc[i][j] += a[i] * b[j];
        }
        __syncthreads();
    }
#pragma unroll
    for (int j = 0; j < 4; ++j) {
        int col = nt * 64 + tc * 4 + j;
        float bv = bias[col];
        float4 v = {acc[0][j] + bv, acc[1][j] + bv, acc[2][j] + bv, acc[3][j] + bv};
        *(float4*)&preT[((size_t)sl * GQ + col) * 64 + tr * 4] = v;
    }
}

// ---------------- persistent LSTM layer ----------------
// grid = 256 WGs x 256 thr. WG owns hidden units j0=wg*2, j0+1 (8 U cols).
// h layout hT2[(k>>2)*256 + b*4 + (k&3)]  (k-quads per batch row).
__global__ __launch_bounds__(256, 2) void k_layer(
    const float* __restrict__ U,
    const float* __restrict__ preT,
    float* __restrict__ h0,
    float* __restrict__ h1,
    float* __restrict__ cT,     // [j][b]
    float* __restrict__ xoutT,  // [s][j][b]
    const int* __restrict__ mask,
    unsigned* __restrict__ bar,
    int s0, int nsteps, int flip)
{
    __shared__ float Ul[DQ * 8];        // [k][c], c = gate*2 + jj
    __shared__ float part[4 * 8 * 64];  // [w][c][b]

    int wg = blockIdx.x;
    int tid = threadIdx.x;
    int w = tid >> 6;
    int b = tid & 63;

    // stage U slice into LDS: cols (g*512 + wg*2 + jj)
    {
        int g = tid & 3;
        int kb = tid >> 2;              // 0..63
        const float* Ucol = U + (size_t)(g * DQ) + wg * 2;
#pragma unroll
        for (int it = 0; it < 8; ++it) {
            int k = kb + it * 64;
            float2 u2 = *(const float2*)&Ucol[(size_t)k * GQ];
            Ul[k * 8 + g * 2 + 0] = u2.x;
            Ul[k * 8 + g * 2 + 1] = u2.y;
        }
    }
    __syncthreads();

    unsigned gen = 0;
    const float* hin = h0;
    float* hout = h1;

    int jj = tid >> 6;                  // finish-phase role (tid<128)
    int j = wg * 2 + jj;

    for (int sl = 0; sl < nsteps; ++sl) {
        int s = s0 + sl;

        // prefetch finish operands
        float z0 = 0, z1 = 0, z2 = 0, z3 = 0, cold = 0, hold = 0;
        int mt = 0;
        if (tid < 128) {
            const float* pb = preT + (size_t)sl * GQ * 64 + b;
            z0 = pb[(size_t)(0 * DQ + j) * 64];
            z1 = pb[(size_t)(1 * DQ + j) * 64];
            z2 = pb[(size_t)(2 * DQ + j) * 64];
            z3 = pb[(size_t)(3 * DQ + j) * 64];
            cold = cT[j * 64 + b];
            hold = hin[(j >> 2) * 256 + b * 4 + (j & 3)];
            int t_in = flip ? (TQ - 1 - s) : s;
            mt = mask[b * TQ + t_in];
        }

        // k-loop: wave w handles k in [w*128, w*128+128)
        float acc[8];
#pragma unroll
        for (int i = 0; i < 8; ++i) acc[i] = 0.f;
        const float* hw = hin + (size_t)(w * 32) * 256 + b * 4;
        const float* uw = Ul + (w * 128) * 8;
#pragma unroll 8
        for (int kq = 0; kq < 32; ++kq) {
            float4 hv = *(const float4*)(hw + kq * 256);
            float ha[4] = {hv.x, hv.y, hv.z, hv.w};
#pragma unroll
            for (int ks = 0; ks < 4; ++ks) {
                int k = kq * 4 + ks;
                float4 u0 = *(const float4*)(uw + k * 8);
                float4 u1 = *(const float4*)(uw + k * 8 + 4);
                float hvv = ha[ks];
                acc[0] += hvv * u0.x; acc[1] += hvv * u0.y;
                acc[2] += hvv * u0.z; acc[3] += hvv * u0.w;
                acc[4] += hvv * u1.x; acc[5] += hvv * u1.y;
                acc[6] += hvv * u1.z; acc[7] += hvv * u1.w;
            }
        }
#pragma unroll
        for (int i = 0; i < 8; ++i) part[(w * 8 + i) * 64 + b] = acc[i];
        __syncthreads();

        if (tid < 128) {
#pragma unroll
            for (int ww = 0; ww < 4; ++ww) {
                z0 += part[(ww * 8 + 0 + jj) * 64 + b];
                z1 += part[(ww * 8 + 2 + jj) * 64 + b];
                z2 += part[(ww * 8 + 4 + jj) * 64 + b];
                z3 += part[(ww * 8 + 6 + jj) * 64 + b];
            }
            float ig = 1.f / (1.f + expf(-z0));
            float fg = 1.f / (1.f + expf(-z1));
            float gg = tanhf(z2);
            float og = 1.f / (1.f + expf(-z3));
            float cn = fg * cold + ig * gg;
            float hn = og * tanhf(cn);
            float ho = mt ? hn : hold;
            float co = mt ? cn : cold;
            hout[(j >> 2) * 256 + b * 4 + (j & 3)] = ho;
            cT[j * 64 + b] = co;
            xoutT[((size_t)s * DQ + j) * 64 + b] = ho;
        }

        // grid barrier
        ++gen;
        __threadfence();
        __syncthreads();
        if (tid == 0) {
            unsigned old = __hip_atomic_fetch_add(&bar[0], 1u, __ATOMIC_ACQ_REL,
                                                  __HIP_MEMORY_SCOPE_AGENT);
            if (old == NWG - 1) {
                __hip_atomic_store(&bar[0], 0u, __ATOMIC_RELAXED, __HIP_MEMORY_SCOPE_AGENT);
                __hip_atomic_store(&bar[64], gen, __ATOMIC_RELEASE, __HIP_MEMORY_SCOPE_AGENT);
            } else {
                while (__hip_atomic_load(&bar[64], __ATOMIC_ACQUIRE,
                                         __HIP_MEMORY_SCOPE_AGENT) != gen)
                    __builtin_amdgcn_s_sleep(2);
            }
        }
        __syncthreads();

        const float* tswap = hin; hin = hout; hout = (float*)tswap;
    }
}

// ---------------- logits = x @ Wout + bout ----------------
__global__ __launch_bounds__(256) void k_out(const float* __restrict__ xT,
                                             const float* __restrict__ Wo,
                                             const float* __restrict__ bo,
                                             float* __restrict__ out) {
    __shared__ float WoL[64 * 64];
    int t = blockIdx.x;
    int tid = threadIdx.x;
    int b = tid & 63;
    int q = tid >> 6;
    float acc[16];
#pragma unroll
    for (int i = 0; i < 16; ++i) acc[i] = 0.f;

    for (int kc = 0; kc < 8; ++kc) {
        __syncthreads();
#pragma unroll
        for (int u = 0; u < 4; ++u)
            *(float4*)&WoL[tid * 16 + u * 4] =
                *(const float4*)&Wo[kc * 4096 + tid * 16 + u * 4];
        __syncthreads();
        for (int kk = 0; kk < 64; ++kk) {
            float xv = xT[((size_t)t * DQ + kc * 64 + kk) * 64 + b];
#pragma unroll
            for (int u = 0; u < 4; ++u) {
                float4 wv = *(const float4*)&WoL[kk * 64 + q * 16 + u * 4];
                acc[u * 4 + 0] += xv * wv.x;
                acc[u * 4 + 1] += xv * wv.y;
                acc[u * 4 + 2] += xv * wv.z;
                acc[u * 4 + 3] += xv * wv.w;
            }
        }
    }
#pragma unroll
    for (int u = 0; u < 4; ++u) {
        int n = q * 16 + u * 4;
        float4 v = {acc[u * 4 + 0] + bo[n + 0], acc[u * 4 + 1] + bo[n + 1],
                    acc[u * 4 + 2] + bo[n + 2], acc[u * 4 + 3] + bo[n + 3]};
        *(float4*)&out[((size_t)(b * TQ + t)) * 64 + n] = v;
    }
}

extern "C" void kernel_launch(void* const* d_in, const int* in_sizes, int n_in,
                              void* d_out, int out_size, void* d_ws, size_t ws_size,
                              hipStream_t stream) {
    const int*   wid  = (const int*)d_in[0];
    const int*   pid  = (const int*)d_in[1];
    const int*   mask = (const int*)d_in[2];
    const float* emb  = (const float*)d_in[3];
    const float* Ws   = (const float*)d_in[4];
    const float* Us   = (const float*)d_in[5];
    const float* bs   = (const float*)d_in[6];
    const float* Wo   = (const float*)d_in[7];
    const float* bo   = (const float*)d_in[8];
    float* out = (float*)d_out;

    const size_t XN = (size_t)TQ * DQ * 64;   // 8388608
    float* x0  = (float*)d_ws;
    float* x1  = x0 + XN;
    float* h0  = x1 + XN;
    float* cT  = h0 + 32768;
    float* h1  = cT + 32768;
    unsigned* bar = (unsigned*)(h1 + 32768);
    float* preT = (float*)(bar + 128);

    size_t base_bytes = (2 * XN + 3 * 32768) * 4 + 512;
    int CHUNK = 256;
    while (CHUNK > 2 && base_bytes + (size_t)CHUNK * GQ * 64 * 4 > ws_size) CHUNK >>= 1;

    k_embed<<<dim3(TQ, 8), 256, 0, stream>>>(wid, pid, emb, x0);

    float* xc = x0;
    float* xn = x1;
    for (int layer = 0; layer < 4; ++layer) {
        int flip = layer & 1;
        const float* W = Ws + (size_t)layer * DQ * GQ;
        const float* U = Us + (size_t)layer * DQ * GQ;
        const float* bias = bs + (size_t)layer * GQ;

        hipMemsetAsync(h0, 0, (size_t)2 * 32768 * 4, stream);  // h0 + cT
        float* ha = h0;
        float* hb = h1;
        for (int s0 = 0; s0 < TQ; s0 += CHUNK) {
            dim3 g(CHUNK, 32);
            k_pre<<<g, 256, 0, stream>>>(xc, W, bias, preT, s0, flip);
            hipMemsetAsync(bar, 0, 512, stream);
            k_layer<<<NWG, 256, 0, stream>>>(U, preT, ha, hb, cT, xn, mask, bar,
                                             s0, CHUNK, flip);
            if (CHUNK & 1) { float* tt = ha; ha = hb; hb = tt; }
        }
        float* t = xc; xc = xn; xn = t;
    }

    k_out<<<TQ, 256, 0, stream>>>(xc, Wo, bo, out);
}

// Round 3
// 9952.244 us; speedup vs baseline: 4.3477x; 4.3477x over previous
//
#include <hip/hip_runtime.h>
#include <math.h>

#define TQ 256
#define DQ 512
#define GQ 2048
#define LNWG 128

// ---------------- embedding + predicate concat -> xT[t][d][b] ----------------
__global__ __launch_bounds__(256) void k_embed(const int* __restrict__ wid,
                                               const int* __restrict__ pid,
                                               const float* __restrict__ emb,
                                               float* __restrict__ xT) {
    __shared__ float Ls[64][65];
    int t = blockIdx.x;
    int d0 = blockIdx.y * 64;
    int tid = threadIdx.x;
    int l = tid & 63;
    int grp = tid >> 6;
#pragma unroll 4
    for (int bb = 0; bb < 16; ++bb) {
        int b = grp * 16 + bb;
        int d = d0 + l;
        float v;
        if (d < 511) v = emb[(size_t)wid[b * TQ + t] * 511 + d];
        else         v = (float)pid[b * TQ + t];
        Ls[l][b] = v;
    }
    __syncthreads();
#pragma unroll 4
    for (int dd = 0; dd < 16; ++dd) {
        int dl = grp * 16 + dd;
        xT[((size_t)t * DQ + d0 + dl) * 64 + l] = Ls[dl][l];
    }
}

// ---------------- preT[sl][col][b] = xT(t_in) @ W + b ----------------
__global__ __launch_bounds__(256) void k_pre(const float* __restrict__ xT,
                                             const float* __restrict__ W,
                                             const float* __restrict__ bias,
                                             float* __restrict__ preT,
                                             int s0, int flip) {
    __shared__ float As[16][68];   // [k][b]
    __shared__ float Bs[16][68];   // [k][n]
    int sl = blockIdx.x;
    int nt = blockIdx.y;
    int s = s0 + sl;
    int t_in = flip ? (TQ - 1 - s) : s;
    int tid = threadIdx.x;
    int tr = tid >> 4;              // 0..15 -> b quad
    int tc = tid & 15;              // 0..15 -> n quad
    int lk = tid >> 4;              // 0..15 (k row for loads)
    int lb4 = (tid & 15) * 4;

    float acc[4][4];
#pragma unroll
    for (int i = 0; i < 4; ++i)
#pragma unroll
        for (int j = 0; j < 4; ++j) acc[i][j] = 0.f;

    const float* xTt = xT + (size_t)t_in * DQ * 64;

    for (int kt = 0; kt < DQ; kt += 16) {
        *(float4*)&As[lk][lb4] = *(const float4*)&xTt[(size_t)(kt + lk) * 64 + lb4];
        *(float4*)&Bs[lk][lb4] = *(const float4*)&W[(size_t)(kt + lk) * GQ + nt * 64 + lb4];
        __syncthreads();
#pragma unroll
        for (int k = 0; k < 16; ++k) {
            float4 av = *(const float4*)&As[k][tr * 4];
            float4 bv = *(const float4*)&Bs[k][tc * 4];
            float a[4] = {av.x, av.y, av.z, av.w};
            float b[4] = {bv.x, bv.y, bv.z, bv.w};
#pragma unroll
            for (int i = 0; i < 4; ++i)
#pragma unroll
                for (int j = 0; j < 4; ++j) acc[i][j] += a[i] * b[j];
        }
        __syncthreads();
    }
#pragma unroll
    for (int j = 0; j < 4; ++j) {
        int col = nt * 64 + tc * 4 + j;
        float bv = bias[col];
        float4 v = {acc[0][j] + bv, acc[1][j] + bv, acc[2][j] + bv, acc[3][j] + bv};
        *(float4*)&preT[((size_t)sl * GQ + col) * 64 + tr * 4] = v;
    }
}

// ---------------- persistent LSTM layer ----------------
// 128 WGs x 512 thr (8 waves). WG owns 4 hidden units (16 U cols, LDS).
// h exchange via relaxed agent atomics (LLC), c in registers, no cache
// maintenance ops anywhere in the step loop.
__global__ __launch_bounds__(512) void k_layer(
    const float* __restrict__ U,
    const float* __restrict__ preT,
    float* __restrict__ hA,
    float* __restrict__ hB,
    float* __restrict__ cT,
    float* __restrict__ xoutT,  // [s][j][b]
    const int* __restrict__ mask,
    unsigned* __restrict__ bar,
    int s0, int nsteps, int flip)
{
    __shared__ float Ul[DQ * 16];          // 32 KB: [k][c], c = g*4 + jl
    __shared__ float part[4 * 16 * 64];    // 16 KB: [w][c][b]

    int wg = blockIdx.x;
    int tid = threadIdx.x;
    int w = tid >> 6;
    int b = tid & 63;

    // stage U slice: cols g*512 + wg*4 + jl
    {
        int c = tid & 15;
        int kb = tid >> 4;              // 0..31
        int gcol = (c >> 2) * DQ + wg * 4 + (c & 3);
#pragma unroll
        for (int kk = 0; kk < 16; ++kk) {
            int k = kb * 16 + kk;
            Ul[k * 16 + c] = U[(size_t)k * GQ + gcol];
        }
    }

    int jl = tid >> 6;                  // finish role (tid<256): 0..3
    int j = wg * 4 + jl;
    float c_reg = 0.f;
    if (tid < 256) c_reg = cT[j * 64 + b];

    __syncthreads();

    int k0 = w * 64;

    for (int sl = 0; sl < nsteps; ++sl) {
        int s = s0 + sl;
        float* hread  = (s & 1) ? hB : hA;
        float* hwrite = (s & 1) ? hA : hB;

        // prefetch finish operands (independent of h exchange)
        float z0 = 0, z1 = 0, z2 = 0, z3 = 0, hold = 0;
        int mt = 0;
        if (tid < 256) {
            const float* pb = preT + (size_t)sl * (GQ * 64) + b;
            z0 = pb[(size_t)(0 * DQ + j) * 64];
            z1 = pb[(size_t)(1 * DQ + j) * 64];
            z2 = pb[(size_t)(2 * DQ + j) * 64];
            z3 = pb[(size_t)(3 * DQ + j) * 64];
            int t_in = flip ? (TQ - 1 - s) : s;
            mt = mask[b * TQ + t_in];
            hold = __hip_atomic_load(&hread[j * 64 + b], __ATOMIC_RELAXED,
                                     __HIP_MEMORY_SCOPE_AGENT);
        }

        // load this wave's h k-slice (coherent LLC reads)
        float hreg[64];
#pragma unroll
        for (int kk = 0; kk < 64; ++kk)
            hreg[kk] = __hip_atomic_load(&hread[(k0 + kk) * 64 + b],
                                         __ATOMIC_RELAXED, __HIP_MEMORY_SCOPE_AGENT);

        float acc[16];
#pragma unroll
        for (int i = 0; i < 16; ++i) acc[i] = 0.f;

#pragma unroll
        for (int kk = 0; kk < 64; ++kk) {
            const float* ur = Ul + (size_t)(k0 + kk) * 16;
            float4 u0 = *(const float4*)(ur + 0);
            float4 u1 = *(const float4*)(ur + 4);
            float4 u2 = *(const float4*)(ur + 8);
            float4 u3 = *(const float4*)(ur + 12);
            float hv = hreg[kk];
            acc[0] += hv * u0.x;  acc[1] += hv * u0.y;
            acc[2] += hv * u0.z;  acc[3] += hv * u0.w;
            acc[4] += hv * u1.x;  acc[5] += hv * u1.y;
            acc[6] += hv * u1.z;  acc[7] += hv * u1.w;
            acc[8] += hv * u2.x;  acc[9] += hv * u2.y;
            acc[10] += hv * u2.z; acc[11] += hv * u2.w;
            acc[12] += hv * u3.x; acc[13] += hv * u3.y;
            acc[14] += hv * u3.z; acc[15] += hv * u3.w;
        }

        // two-stage cross-wave reduction in LDS
        if (w < 4) {
#pragma unroll
            for (int i = 0; i < 16; ++i) part[(w * 16 + i) * 64 + b] = acc[i];
        }
        __syncthreads();
        if (w >= 4) {
            int w2 = w - 4;
#pragma unroll
            for (int i = 0; i < 16; ++i) part[(w2 * 16 + i) * 64 + b] += acc[i];
        }
        __syncthreads();

        if (tid < 256) {
#pragma unroll
            for (int ww = 0; ww < 4; ++ww) {
                z0 += part[(ww * 16 + 0 + jl) * 64 + b];
                z1 += part[(ww * 16 + 4 + jl) * 64 + b];
                z2 += part[(ww * 16 + 8 + jl) * 64 + b];
                z3 += part[(ww * 16 + 12 + jl) * 64 + b];
            }
            float ig = 1.f / (1.f + expf(-z0));
            float fg = 1.f / (1.f + expf(-z1));
            float gg = tanhf(z2);
            float og = 1.f / (1.f + expf(-z3));
            float cn = fg * c_reg + ig * gg;
            float hn = og * tanhf(cn);
            float ho = mt ? hn : hold;
            c_reg = mt ? cn : c_reg;
            __hip_atomic_store(&hwrite[j * 64 + b], ho, __ATOMIC_RELAXED,
                               __HIP_MEMORY_SCOPE_AGENT);
            xoutT[((size_t)s * DQ + j) * 64 + b] = ho;
        }

        // grid barrier: vmcnt drain via __syncthreads, relaxed two-level arrive
        __syncthreads();
        if (tid == 0) {
            unsigned o1 = __hip_atomic_fetch_add(&bar[(wg & 7) * 32], 1u,
                                                 __ATOMIC_RELAXED, __HIP_MEMORY_SCOPE_AGENT);
            if (o1 == (unsigned)(sl * 16 + 15)) {
                unsigned o2 = __hip_atomic_fetch_add(&bar[8 * 32], 1u,
                                                     __ATOMIC_RELAXED, __HIP_MEMORY_SCOPE_AGENT);
                if (o2 == (unsigned)(sl * 8 + 7))
                    __hip_atomic_store(&bar[9 * 32], (unsigned)(sl + 1),
                                       __ATOMIC_RELAXED, __HIP_MEMORY_SCOPE_AGENT);
            }
            while (__hip_atomic_load(&bar[9 * 32], __ATOMIC_RELAXED,
                                     __HIP_MEMORY_SCOPE_AGENT) < (unsigned)(sl + 1))
                __builtin_amdgcn_s_sleep(2);
        }
        __syncthreads();
    }

    if (tid < 256) cT[j * 64 + b] = c_reg;
}

// ---------------- logits = x @ Wout + bout ----------------
__global__ __launch_bounds__(256) void k_out(const float* __restrict__ xT,
                                             const float* __restrict__ Wo,
                                             const float* __restrict__ bo,
                                             float* __restrict__ out) {
    __shared__ float WoL[64 * 64];
    int t = blockIdx.x;
    int tid = threadIdx.x;
    int b = tid & 63;
    int q = tid >> 6;
    float acc[16];
#pragma unroll
    for (int i = 0; i < 16; ++i) acc[i] = 0.f;

    for (int kc = 0; kc < 8; ++kc) {
        __syncthreads();
#pragma unroll
        for (int u = 0; u < 4; ++u)
            *(float4*)&WoL[tid * 16 + u * 4] =
                *(const float4*)&Wo[kc * 4096 + tid * 16 + u * 4];
        __syncthreads();
        for (int kk = 0; kk < 64; ++kk) {
            float xv = xT[((size_t)t * DQ + kc * 64 + kk) * 64 + b];
#pragma unroll
            for (int u = 0; u < 4; ++u) {
                float4 wv = *(const float4*)&WoL[kk * 64 + q * 16 + u * 4];
                acc[u * 4 + 0] += xv * wv.x;
                acc[u * 4 + 1] += xv * wv.y;
                acc[u * 4 + 2] += xv * wv.z;
                acc[u * 4 + 3] += xv * wv.w;
            }
        }
    }
#pragma unroll
    for (int u = 0; u < 4; ++u) {
        int n = q * 16 + u * 4;
        float4 v = {acc[u * 4 + 0] + bo[n + 0], acc[u * 4 + 1] + bo[n + 1],
                    acc[u * 4 + 2] + bo[n + 2], acc[u * 4 + 3] + bo[n + 3]};
        *(float4*)&out[((size_t)(b * TQ + t)) * 64 + n] = v;
    }
}

extern "C" void kernel_launch(void* const* d_in, const int* in_sizes, int n_in,
                              void* d_out, int out_size, void* d_ws, size_t ws_size,
                              hipStream_t stream) {
    const int*   wid  = (const int*)d_in[0];
    const int*   pid  = (const int*)d_in[1];
    const int*   mask = (const int*)d_in[2];
    const float* emb  = (const float*)d_in[3];
    const float* Ws   = (const float*)d_in[4];
    const float* Us   = (const float*)d_in[5];
    const float* bs   = (const float*)d_in[6];
    const float* Wo   = (const float*)d_in[7];
    const float* bo   = (const float*)d_in[8];
    float* out = (float*)d_out;

    const size_t XN = (size_t)TQ * DQ * 64;   // 8388608
    float* x0  = (float*)d_ws;
    float* x1  = x0 + XN;
    float* hA  = x1 + XN;
    float* cT  = hA + 32768;
    float* hB  = cT + 32768;
    unsigned* bar = (unsigned*)(hB + 32768);
    float* preT = (float*)(bar + 1024);

    size_t base_bytes = (2 * XN + 3 * 32768) * 4 + 4096;
    int CHUNK = 256;
    while (CHUNK > 2 && base_bytes + (size_t)CHUNK * GQ * 64 * 4 > ws_size) CHUNK >>= 1;

    k_embed<<<dim3(TQ, 8), 256, 0, stream>>>(wid, pid, emb, x0);

    float* xc = x0;
    float* xn = x1;
    for (int layer = 0; layer < 4; ++layer) {
        int flip = layer & 1;
        const float* W = Ws + (size_t)layer * DQ * GQ;
        const float* U = Us + (size_t)layer * DQ * GQ;
        const float* bias = bs + (size_t)layer * GQ;

        hipMemsetAsync(hA, 0, (size_t)2 * 32768 * 4, stream);  // hA + cT
        for (int s0 = 0; s0 < TQ; s0 += CHUNK) {
            dim3 g(CHUNK, 32);
            k_pre<<<g, 256, 0, stream>>>(xc, W, bias, preT, s0, flip);
            hipMemsetAsync(bar, 0, 4096, stream);
            k_layer<<<LNWG, 512, 0, stream>>>(U, preT, hA, hB, cT, xn, mask, bar,
                                              s0, CHUNK, flip);
        }
        float* t = xc; xc = xn; xn = t;
    }

    k_out<<<TQ, 256, 0, stream>>>(xc, Wo, bo, out);
}